// Round 2
// 334.614 us; speedup vs baseline: 1.0361x; 1.0361x over previous
//
#include <hip/hip_runtime.h>
#include <cstdint>
#include <cstddef>

// SSM layer: y = scan(x @ B^T) @ C^T + D * x
// x: (8,4096,1024) f32; A: (256,); B: (256,1024); C: (1024,256); D: (1024,)
// M = 32768 rows. Pipeline:
//   cvt (B,C -> f16) -> gemm_bx(+fused scan_E) -> scan_prefix -> scan_apply -> gemm_y
// R2 = R1 resubmitted verbatim (R1 bench died to container-acquire infra flake;
// source audit found no OOB/race/hang candidates).
// R1 changes vs 348us baseline:
//   * gemm_y: 32KB C-slab (64 cols), 4-nt/wave tile, __launch_bounds__(256,4)
//     -> 4 blocks/CU, 16 waves/CU (was 8). Theory: latency-bound streaming
//     (Occupancy 9.3%, hbm 2.9/6.3 TB/s, MfmaUtil 6.7%) -> double MLP.
//     x/y HBM traffic unchanged (each block owns a disjoint column stripe).
//   * scan_E folded into gemm_bx epilogue (tile already in LDS for the
//     coalesced-store bounce; bit-identical f16 numerics).
//   * scan_prefix: bulk-load E slice to LDS, serial recurrence from LDS.

typedef __attribute__((ext_vector_type(8))) _Float16 half8;
typedef __attribute__((ext_vector_type(4))) float f32x4;

__device__ inline half8 cvt8(float4 a, float4 b) {
  half8 h;
  h[0] = (_Float16)a.x; h[1] = (_Float16)a.y;
  h[2] = (_Float16)a.z; h[3] = (_Float16)a.w;
  h[4] = (_Float16)b.x; h[5] = (_Float16)b.y;
  h[6] = (_Float16)b.z; h[7] = (_Float16)b.w;
  return h;
}

// ---------------------------------------------------------------------------
// Convert B (256x1024) and C (1024x256) to f16. 65536 threads x 8 elems.
// ---------------------------------------------------------------------------
__global__ __launch_bounds__(256) void cvt_bc(
    const float* __restrict__ Bp, const float* __restrict__ Cp,
    _Float16* __restrict__ Bh, _Float16* __restrict__ Ch)
{
  const int g = blockIdx.x * 256 + threadIdx.x;      // 0..65535
  const size_t off = (size_t)(g & 32767) * 8;
  const float* src = (g < 32768) ? (Bp + off) : (Cp + off);
  _Float16*    dst = (g < 32768) ? (Bh + off) : (Ch + off);
  float4 a = *(const float4*)src;
  float4 b = *(const float4*)(src + 4);
  *(half8*)dst = cvt8(a, b);
}

// ---------------------------------------------------------------------------
// GEMM1: Bx[M,256] = x[M,1024] * B[256,1024]^T  (f16 out) + fused scan_E.
// Block = 64 rows (= one scan chunk); wave w owns rows w*16..+15 x ALL 256 n.
// B-slab chunk (256n x 128k f16 = 64KB, XOR-swizzled) in LDS, refilled from
// L2 each K-chunk. A-fragments stream straight from global x.
// Epilogue bounces the 64x256 f16 tile through LDS for coalesced stores AND
// computes E[chunk][n] = 64-step scan sum from the same LDS tile.
// ---------------------------------------------------------------------------
__global__ __launch_bounds__(256) void gemm_bx(
    const float* __restrict__ x, const _Float16* __restrict__ Bh,
    const float* __restrict__ Ap,
    _Float16* __restrict__ Bxh, float* __restrict__ E)
{
  __shared__ _Float16 lb[256 * 128];   // 64KB, [n][k8p*8], k8p = k8 ^ (n&7)

  const int tid  = threadIdx.x;
  const int lane = tid & 63;
  const int wave = tid >> 6;
  const int quad = lane >> 4;
  const int l16  = lane & 15;
  const long blockM = (long)blockIdx.x * 64;
  const long arow = blockM + wave * 16 + l16;     // global A row for frags

  f32x4 acc[16];
  #pragma unroll
  for (int i = 0; i < 16; i++) acc[i] = (f32x4){0.f, 0.f, 0.f, 0.f};

  for (int kc = 0; kc < 8; kc++) {
    __syncthreads();   // previous chunk's readers done
    // fill B-slab: thread t = row n, 16 x 16B from L2-resident Bh
    {
      const int n = tid;
      const _Float16* src = Bh + (size_t)n * 1024 + kc * 128;
      #pragma unroll
      for (int j = 0; j < 16; j++) {
        half8 v = *(const half8*)(src + j * 8);
        const int k8p = j ^ (n & 7);
        *(half8*)&lb[n * 128 + k8p * 8] = v;
      }
    }
    // A-fragments for this chunk (4 ks), direct from x
    half8 af[4];
    #pragma unroll
    for (int ks = 0; ks < 4; ks++) {
      const float* ga = x + arow * 1024 + kc * 128 + ks * 32 + quad * 8;
      float4 a0 = *(const float4*)ga;
      float4 a1 = *(const float4*)(ga + 4);
      af[ks] = cvt8(a0, a1);
    }
    __syncthreads();
    #pragma unroll
    for (int ks = 0; ks < 4; ks++) {
      #pragma unroll
      for (int nt = 0; nt < 16; nt++) {
        const int n   = nt * 16 + l16;
        const int k8p = (ks * 4 + quad) ^ (n & 7);
        half8 bf = *(const half8*)&lb[n * 128 + k8p * 8];
        acc[nt] = __builtin_amdgcn_mfma_f32_16x16x32_f16(af[ks], bf, acc[nt], 0, 0, 0);
      }
    }
  }

  // epilogue: bounce through LDS -> coalesced f16 stores + fused scan_E.
  __syncthreads();
  #pragma unroll
  for (int nt = 0; nt < 16; nt++)
    #pragma unroll
    for (int r = 0; r < 4; r++)
      lb[(wave * 16 + quad * 4 + r) * 256 + nt * 16 + l16] = (_Float16)acc[nt][r];
  __syncthreads();
  {
    const int row = tid >> 2, seg = tid & 3;       // 64 rows x 4 segs
    _Float16* dst = Bxh + (blockM + row) * 256 + seg * 64;
    const _Float16* srcl = &lb[row * 256 + seg * 64];
    #pragma unroll
    for (int j = 0; j < 8; j++)
      *(half8*)(dst + j * 8) = *(const half8*)(srcl + j * 8);
  }
  {
    // fused scan_E: thread tid = state index n; 64-step serial scan over the
    // LDS tile (same f16 values that were just stored -> bit-identical).
    const float al = expf(-expf(Ap[tid]));
    float h = 0.f;
    #pragma unroll 8
    for (int t = 0; t < 64; t++)
      h = fmaf(al, h, (float)lb[t * 256 + tid]);
    E[(size_t)blockIdx.x * 256 + tid] = h;
  }
}

// ---------------------------------------------------------------------------
// scan_prefix: per batch b, serial prefix over 64 chunk sums.
// Bulk-load the 64x256 f32 E-slice (64KB) into LDS with pipelined float4
// loads, then run the serial recurrence out of LDS (no per-step global
// latency round-trips).
// ---------------------------------------------------------------------------
__global__ __launch_bounds__(256) void scan_prefix(
    const float* __restrict__ E, const float* __restrict__ Ap,
    float* __restrict__ carry)
{
  __shared__ float4 se4[4096];                     // 64KB = 64 chunks x 256 n
  const int n = threadIdx.x;
  const int b = blockIdx.x;

  const float4* src4 = (const float4*)(E + (size_t)b * 64 * 256);
  #pragma unroll
  for (int j = 0; j < 16; j++)
    se4[j * 256 + n] = src4[j * 256 + n];

  const float al = expf(-expf(Ap[n]));
  float aL = al;
  #pragma unroll
  for (int i = 0; i < 6; i++) aL *= aL;            // al^64

  __syncthreads();
  const float* se = (const float*)se4;
  float run = 0.f;
  for (int c = 0; c < 64; c++) {
    carry[((size_t)b * 64 + c) * 256 + n] = run;
    run = fmaf(aL, run, se[c * 256 + n]);
  }
}

__global__ __launch_bounds__(256) void scan_apply(
    _Float16* __restrict__ Bxh, const float* __restrict__ Ap,
    const float* __restrict__ carry)
{
  const int n  = threadIdx.x;
  const int bc = blockIdx.x;
  const float al = expf(-expf(Ap[n]));
  float h = carry[(size_t)bc * 256 + n];
  const size_t base = (size_t)bc * 64 * 256 + n;
  #pragma unroll 16
  for (int t = 0; t < 64; t++) {
    const size_t i = base + (size_t)t * 256;
    h = fmaf(al, h, (float)Bxh[i]);
    Bxh[i] = (_Float16)h;
  }
}

// ---------------------------------------------------------------------------
// GEMM2: y[M,1024] = hs[M,256] * C[1024,256]^T + D*x
// R1: n-slab = 64 cols (slab = blockIdx&15), 32KB swizzled C-slab loaded
// ONCE; 4 M-chunks of 64 rows per block (mg = blockIdx>>4). Barrier-free
// M-loop: hs A-frags + x tiles stream direct from global. 4-nt/wave tile
// keeps VGPR ~105 -> __launch_bounds__(256,4) -> 4 blocks/CU = 16 waves/CU.
// x/y traffic: each block owns a disjoint 64-col stripe -> read/write once.
// hs re-read x16 slabs, L3-resident.
// ---------------------------------------------------------------------------
__global__ __launch_bounds__(256, 4) void gemm_y(
    const _Float16* __restrict__ hs, const _Float16* __restrict__ Ch,
    const float* __restrict__ x, const float* __restrict__ Dp,
    float* __restrict__ y)
{
  __shared__ _Float16 lc[64 * 256];   // 32KB, [n_local][k8p*8]

  const int tid  = threadIdx.x;
  const int lane = tid & 63;
  const int wave = tid >> 6;         // 0..3
  const int quad = lane >> 4;
  const int l16  = lane & 15;
  const int slab = blockIdx.x & 15;
  const int mg   = blockIdx.x >> 4;  // 0..127
  const int n0   = slab * 64;

  // fill C-slab once: thread t -> n = t>>2 (0..63), q = t&3 (8 x 16B each)
  {
    const int n = tid >> 2, q = tid & 3;
    const _Float16* src = Ch + (size_t)(n0 + n) * 256 + q * 64;
    #pragma unroll
    for (int j = 0; j < 8; j++) {
      half8 v = *(const half8*)(src + j * 8);
      const int k8p = (q * 8 + j) ^ (n & 7);
      *(half8*)&lc[n * 256 + k8p * 8] = v;
    }
  }

  // per-lane D values (columns fixed for the whole block)
  float dv[4];
  #pragma unroll
  for (int nt = 0; nt < 4; nt++) dv[nt] = Dp[n0 + nt * 16 + l16];

  __syncthreads();

  for (int i = 0; i < 4; i++) {
    const long chunk   = (long)mg * 4 + i;
    const long rowbase = chunk * 64 + wave * 16;

    // A-fragments: 8 x 16B direct from hs (f16, L3-resident)
    half8 af[8];
    #pragma unroll
    for (int ks = 0; ks < 8; ks++)
      af[ks] = *(const half8*)(hs + (rowbase + l16) * 256 + ks * 32 + quad * 8);

    // preload this lane's x tile (4 rows x 4 col-tiles) ahead of the MFMAs
    float xv[4][4];
    #pragma unroll
    for (int r = 0; r < 4; r++) {
      const float* gx = x + (rowbase + quad * 4 + r) * 1024 + n0 + l16;
      #pragma unroll
      for (int nt = 0; nt < 4; nt++) xv[r][nt] = gx[nt * 16];
    }

    f32x4 acc[4];
    #pragma unroll
    for (int nt = 0; nt < 4; nt++) acc[nt] = (f32x4){0.f, 0.f, 0.f, 0.f};

    #pragma unroll
    for (int ks = 0; ks < 8; ks++) {
      #pragma unroll
      for (int nt = 0; nt < 4; nt++) {
        const int n   = nt * 16 + l16;
        const int k8p = (ks * 4 + quad) ^ (n & 7);
        half8 bf = *(const half8*)&lc[n * 256 + k8p * 8];
        acc[nt] = __builtin_amdgcn_mfma_f32_16x16x32_f16(af[ks], bf, acc[nt], 0, 0, 0);
      }
    }

    // epilogue: y = acc + D*x (4 rows x 4 col-tiles per lane)
    #pragma unroll
    for (int r = 0; r < 4; r++) {
      float* gy = y + (rowbase + quad * 4 + r) * 1024 + n0 + l16;
      #pragma unroll
      for (int nt = 0; nt < 4; nt++)
        gy[nt * 16] = acc[nt][r] + dv[nt] * xv[r][nt];
    }
  }
}

// ---------------------------------------------------------------------------
extern "C" void kernel_launch(void* const* d_in, const int* in_sizes, int n_in,
                              void* d_out, int out_size, void* d_ws, size_t ws_size,
                              hipStream_t stream) {
  const float* x  = (const float*)d_in[0];
  const float* Ap = (const float*)d_in[1];
  const float* Bp = (const float*)d_in[2];
  const float* Cp = (const float*)d_in[3];
  const float* Dp = (const float*)d_in[4];
  float* y = (float*)d_out;

  // ws: Bxh 16.8MB | Bh 512KB | Ch 512KB | E 512KB | carry 512KB
  _Float16* Bxh = (_Float16*)d_ws;
  _Float16* Bh  = Bxh + (size_t)32768 * 256;
  _Float16* Ch  = Bh + (size_t)256 * 1024;
  float* E      = (float*)(Ch + (size_t)1024 * 256);
  float* carry  = E + (size_t)512 * 256;

  cvt_bc     <<<256,  256, 0, stream>>>(Bp, Cp, Bh, Ch);
  gemm_bx    <<<512,  256, 0, stream>>>(x, Bh, Ap, Bxh, E);
  scan_prefix<<<8,    256, 0, stream>>>(E, Ap, carry);
  scan_apply <<<512,  256, 0, stream>>>(Bxh, Ap, carry);
  gemm_y     <<<2048, 256, 0, stream>>>(Bxh, Ch, x, Dp, y);
}

// Round 3
// 328.606 us; speedup vs baseline: 1.0551x; 1.0183x over previous
//
#include <hip/hip_runtime.h>
#include <cstdint>
#include <cstddef>

// SSM layer: y = scan(x @ B^T) @ C^T + D * x
// x: (8,4096,1024) f32; A: (256,); B: (256,1024); C: (1024,256); D: (1024,)
// M = 32768 rows. Pipeline:
//   cvt (B,C -> f16) -> gemm_bx(+fused scan_E) -> scan_prefix -> scan_apply -> gemm_y
// R3 change (gemm_y only):
//   * Swapped-operand MFMA: acc = mfma(C_frag, hs_frag) -> D-tile transposed so
//     each lane owns 4 CONSECUTIVE y columns -> x load / D load / y store are
//     float4 (4 instrs instead of 16 scalars; 4x bytes per vmcnt slot).
//     Theory: R1->R2 tripled occupancy but BW only +14% -> per-wave MLP
//     (issue-slot-limited scalar loads) is the limiter, not occupancy.
//   * 2-deep chunk software pipeline (named double buffers, static indexing).
//   * __launch_bounds__(256,3): ~132 VGPR, 3 blocks/CU (matches measured occ).

typedef __attribute__((ext_vector_type(8))) _Float16 half8;
typedef __attribute__((ext_vector_type(4))) float f32x4;

__device__ inline half8 cvt8(float4 a, float4 b) {
  half8 h;
  h[0] = (_Float16)a.x; h[1] = (_Float16)a.y;
  h[2] = (_Float16)a.z; h[3] = (_Float16)a.w;
  h[4] = (_Float16)b.x; h[5] = (_Float16)b.y;
  h[6] = (_Float16)b.z; h[7] = (_Float16)b.w;
  return h;
}

// ---------------------------------------------------------------------------
// Convert B (256x1024) and C (1024x256) to f16. 65536 threads x 8 elems.
// ---------------------------------------------------------------------------
__global__ __launch_bounds__(256) void cvt_bc(
    const float* __restrict__ Bp, const float* __restrict__ Cp,
    _Float16* __restrict__ Bh, _Float16* __restrict__ Ch)
{
  const int g = blockIdx.x * 256 + threadIdx.x;      // 0..65535
  const size_t off = (size_t)(g & 32767) * 8;
  const float* src = (g < 32768) ? (Bp + off) : (Cp + off);
  _Float16*    dst = (g < 32768) ? (Bh + off) : (Ch + off);
  float4 a = *(const float4*)src;
  float4 b = *(const float4*)(src + 4);
  *(half8*)dst = cvt8(a, b);
}

// ---------------------------------------------------------------------------
// GEMM1: Bx[M,256] = x[M,1024] * B[256,1024]^T  (f16 out) + fused scan_E.
// Block = 64 rows (= one scan chunk); wave w owns rows w*16..+15 x ALL 256 n.
// B-slab chunk (256n x 128k f16 = 64KB, XOR-swizzled) in LDS, refilled from
// L2 each K-chunk. A-fragments stream straight from global x.
// Epilogue bounces the 64x256 f16 tile through LDS for coalesced stores AND
// computes E[chunk][n] = 64-step scan sum from the same LDS tile.
// ---------------------------------------------------------------------------
__global__ __launch_bounds__(256) void gemm_bx(
    const float* __restrict__ x, const _Float16* __restrict__ Bh,
    const float* __restrict__ Ap,
    _Float16* __restrict__ Bxh, float* __restrict__ E)
{
  __shared__ _Float16 lb[256 * 128];   // 64KB, [n][k8p*8], k8p = k8 ^ (n&7)

  const int tid  = threadIdx.x;
  const int lane = tid & 63;
  const int wave = tid >> 6;
  const int quad = lane >> 4;
  const int l16  = lane & 15;
  const long blockM = (long)blockIdx.x * 64;
  const long arow = blockM + wave * 16 + l16;     // global A row for frags

  f32x4 acc[16];
  #pragma unroll
  for (int i = 0; i < 16; i++) acc[i] = (f32x4){0.f, 0.f, 0.f, 0.f};

  for (int kc = 0; kc < 8; kc++) {
    __syncthreads();   // previous chunk's readers done
    // fill B-slab: thread t = row n, 16 x 16B from L2-resident Bh
    {
      const int n = tid;
      const _Float16* src = Bh + (size_t)n * 1024 + kc * 128;
      #pragma unroll
      for (int j = 0; j < 16; j++) {
        half8 v = *(const half8*)(src + j * 8);
        const int k8p = j ^ (n & 7);
        *(half8*)&lb[n * 128 + k8p * 8] = v;
      }
    }
    // A-fragments for this chunk (4 ks), direct from x
    half8 af[4];
    #pragma unroll
    for (int ks = 0; ks < 4; ks++) {
      const float* ga = x + arow * 1024 + kc * 128 + ks * 32 + quad * 8;
      float4 a0 = *(const float4*)ga;
      float4 a1 = *(const float4*)(ga + 4);
      af[ks] = cvt8(a0, a1);
    }
    __syncthreads();
    #pragma unroll
    for (int ks = 0; ks < 4; ks++) {
      #pragma unroll
      for (int nt = 0; nt < 16; nt++) {
        const int n   = nt * 16 + l16;
        const int k8p = (ks * 4 + quad) ^ (n & 7);
        half8 bf = *(const half8*)&lb[n * 128 + k8p * 8];
        acc[nt] = __builtin_amdgcn_mfma_f32_16x16x32_f16(af[ks], bf, acc[nt], 0, 0, 0);
      }
    }
  }

  // epilogue: bounce through LDS -> coalesced f16 stores + fused scan_E.
  __syncthreads();
  #pragma unroll
  for (int nt = 0; nt < 16; nt++)
    #pragma unroll
    for (int r = 0; r < 4; r++)
      lb[(wave * 16 + quad * 4 + r) * 256 + nt * 16 + l16] = (_Float16)acc[nt][r];
  __syncthreads();
  {
    const int row = tid >> 2, seg = tid & 3;       // 64 rows x 4 segs
    _Float16* dst = Bxh + (blockM + row) * 256 + seg * 64;
    const _Float16* srcl = &lb[row * 256 + seg * 64];
    #pragma unroll
    for (int j = 0; j < 8; j++)
      *(half8*)(dst + j * 8) = *(const half8*)(srcl + j * 8);
  }
  {
    // fused scan_E: thread tid = state index n; 64-step serial scan over the
    // LDS tile (same f16 values that were just stored -> bit-identical).
    const float al = expf(-expf(Ap[tid]));
    float h = 0.f;
    #pragma unroll 8
    for (int t = 0; t < 64; t++)
      h = fmaf(al, h, (float)lb[t * 256 + tid]);
    E[(size_t)blockIdx.x * 256 + tid] = h;
  }
}

// ---------------------------------------------------------------------------
// scan_prefix: per batch b, serial prefix over 64 chunk sums.
// Bulk-load the 64x256 f32 E-slice (64KB) into LDS with pipelined float4
// loads, then run the serial recurrence out of LDS.
// ---------------------------------------------------------------------------
__global__ __launch_bounds__(256) void scan_prefix(
    const float* __restrict__ E, const float* __restrict__ Ap,
    float* __restrict__ carry)
{
  __shared__ float4 se4[4096];                     // 64KB = 64 chunks x 256 n
  const int n = threadIdx.x;
  const int b = blockIdx.x;

  const float4* src4 = (const float4*)(E + (size_t)b * 64 * 256);
  #pragma unroll
  for (int j = 0; j < 16; j++)
    se4[j * 256 + n] = src4[j * 256 + n];

  const float al = expf(-expf(Ap[n]));
  float aL = al;
  #pragma unroll
  for (int i = 0; i < 6; i++) aL *= aL;            // al^64

  __syncthreads();
  const float* se = (const float*)se4;
  float run = 0.f;
  for (int c = 0; c < 64; c++) {
    carry[((size_t)b * 64 + c) * 256 + n] = run;
    run = fmaf(aL, run, se[c * 256 + n]);
  }
}

__global__ __launch_bounds__(256) void scan_apply(
    _Float16* __restrict__ Bxh, const float* __restrict__ Ap,
    const float* __restrict__ carry)
{
  const int n  = threadIdx.x;
  const int bc = blockIdx.x;
  const float al = expf(-expf(Ap[n]));
  float h = carry[(size_t)bc * 256 + n];
  const size_t base = (size_t)bc * 64 * 256 + n;
  #pragma unroll 16
  for (int t = 0; t < 64; t++) {
    const size_t i = base + (size_t)t * 256;
    h = fmaf(al, h, (float)Bxh[i]);
    Bxh[i] = (_Float16)h;
  }
}

// ---------------------------------------------------------------------------
// GEMM2: y[M,1024] = hs[M,256] * C[1024,256]^T + D*x
// R3: swapped-operand MFMA -> lane owns y[row][4 consecutive cols] ->
// float4 x/D loads + float4 y stores (4x bytes per memory instruction).
// n-slab = 64 cols (slab = blockIdx&15), 32KB swizzled C-slab loaded once;
// 4 M-chunks of 64 rows per block (mg = blockIdx>>4), 2-deep chunk pipeline.
// x/y traffic: each block owns a disjoint 64-col stripe -> read/write once.
// hs re-read x16 slabs, L3-resident.
// ---------------------------------------------------------------------------
__global__ __launch_bounds__(256, 3) void gemm_y(
    const _Float16* __restrict__ hs, const _Float16* __restrict__ Ch,
    const float* __restrict__ x, const float* __restrict__ Dp,
    float* __restrict__ y)
{
  __shared__ _Float16 lc[64 * 256];   // 32KB, [n_local][k8p*8]

  const int tid  = threadIdx.x;
  const int lane = tid & 63;
  const int wave = tid >> 6;         // 0..3
  const int quad = lane >> 4;
  const int l16  = lane & 15;
  const int slab = blockIdx.x & 15;
  const int mg   = blockIdx.x >> 4;  // 0..127
  const int n0   = slab * 64;

  // fill C-slab once: thread t -> n = t>>2 (0..63), q = t&3 (8 x 16B each)
  {
    const int n = tid >> 2, q = tid & 3;
    const _Float16* src = Ch + (size_t)(n0 + n) * 256 + q * 64;
    #pragma unroll
    for (int j = 0; j < 8; j++) {
      half8 v = *(const half8*)(src + j * 8);
      const int k8p = (q * 8 + j) ^ (n & 7);
      *(half8*)&lc[n * 256 + k8p * 8] = v;
    }
  }
  __syncthreads();

  // loads for chunk i: hs A-side fragments (af, used as MFMA B-operand) and
  // this lane's x float4s (4 consecutive cols at n0 + nt*16 + quad*4).
  auto load_chunk = [&](int i, half8* af, float4* xv) {
    const long row = ((long)mg * 4 + i) * 64 + wave * 16 + l16;
    const _Float16* ph = hs + row * 256;
    #pragma unroll
    for (int ks = 0; ks < 8; ks++)
      af[ks] = *(const half8*)(ph + ks * 32 + quad * 8);
    const float* px = x + row * 1024 + n0 + quad * 4;
    #pragma unroll
    for (int nt = 0; nt < 4; nt++)
      xv[nt] = *(const float4*)(px + nt * 16);
  };

  // compute chunk i: swapped-operand MFMA. A = C-slab frag (row=l16 -> n),
  // B = hs frag (col=l16 -> y-row). D[row=quad*4+r][col=l16] =
  // y[rowbase+l16][n0 + nt*16 + quad*4 + r]: 4 consecutive columns per lane.
  auto compute_chunk = [&](int i, const half8* af, const float4* xv) {
    const long row = ((long)mg * 4 + i) * 64 + wave * 16 + l16;
    f32x4 acc[4];
    #pragma unroll
    for (int nt = 0; nt < 4; nt++) acc[nt] = (f32x4){0.f, 0.f, 0.f, 0.f};

    #pragma unroll
    for (int ks = 0; ks < 8; ks++) {
      #pragma unroll
      for (int nt = 0; nt < 4; nt++) {
        const int n   = nt * 16 + l16;
        const int k8p = (ks * 4 + quad) ^ (n & 7);
        half8 cf = *(const half8*)&lc[n * 256 + k8p * 8];
        acc[nt] = __builtin_amdgcn_mfma_f32_16x16x32_f16(cf, af[ks], acc[nt], 0, 0, 0);
      }
    }

    float* py = y + row * 1024 + n0 + quad * 4;
    const float* pD = Dp + n0 + quad * 4;
    #pragma unroll
    for (int nt = 0; nt < 4; nt++) {
      float4 dv = *(const float4*)(pD + nt * 16);
      float4 o;
      o.x = acc[nt][0] + dv.x * xv[nt].x;
      o.y = acc[nt][1] + dv.y * xv[nt].y;
      o.z = acc[nt][2] + dv.z * xv[nt].z;
      o.w = acc[nt][3] + dv.w * xv[nt].w;
      *(float4*)(py + nt * 16) = o;
    }
  };

  // 2-deep software pipeline over the 4 chunks (named buffers, static idx).
  half8 afA[8], afB[8];
  float4 xvA[4], xvB[4];
  load_chunk(0, afA, xvA);
  load_chunk(1, afB, xvB);
  compute_chunk(0, afA, xvA);
  load_chunk(2, afA, xvA);
  compute_chunk(1, afB, xvB);
  load_chunk(3, afB, xvB);
  compute_chunk(2, afA, xvA);
  compute_chunk(3, afB, xvB);
}

// ---------------------------------------------------------------------------
extern "C" void kernel_launch(void* const* d_in, const int* in_sizes, int n_in,
                              void* d_out, int out_size, void* d_ws, size_t ws_size,
                              hipStream_t stream) {
  const float* x  = (const float*)d_in[0];
  const float* Ap = (const float*)d_in[1];
  const float* Bp = (const float*)d_in[2];
  const float* Cp = (const float*)d_in[3];
  const float* Dp = (const float*)d_in[4];
  float* y = (float*)d_out;

  // ws: Bxh 16.8MB | Bh 512KB | Ch 512KB | E 512KB | carry 512KB
  _Float16* Bxh = (_Float16*)d_ws;
  _Float16* Bh  = Bxh + (size_t)32768 * 256;
  _Float16* Ch  = Bh + (size_t)256 * 1024;
  float* E      = (float*)(Ch + (size_t)1024 * 256);
  float* carry  = E + (size_t)512 * 256;

  cvt_bc     <<<256,  256, 0, stream>>>(Bp, Cp, Bh, Ch);
  gemm_bx    <<<512,  256, 0, stream>>>(x, Bh, Ap, Bxh, E);
  scan_prefix<<<8,    256, 0, stream>>>(E, Ap, carry);
  scan_apply <<<512,  256, 0, stream>>>(Bxh, Ap, carry);
  gemm_y     <<<2048, 256, 0, stream>>>(Bxh, Ch, x, Dp, y);
}

// Round 4
// 323.142 us; speedup vs baseline: 1.0729x; 1.0169x over previous
//
#include <hip/hip_runtime.h>
#include <cstdint>
#include <cstddef>

// SSM layer: y = scan(x @ B^T) @ C^T + D * x
// x: (8,4096,1024) f32; A: (256,); B: (256,1024); C: (1024,256); D: (1024,)
// M = 32768 rows. Pipeline:
//   cvt (B,C -> f16) -> gemm_bx(+fused scan_E) -> scan_prefix -> scan_apply -> gemm_y
// R4 change (gemm_y only): LOOP-NEST INVERSION.
//   Fabric-traffic model: R1-R3 gemm_y moved x(134)+hs re-read(268,L3)+y(131)
//   = 533MB across the XCD fabric in 83us = 6.4 TB/s = saturated. Occupancy
//   (R2) and load width (R3) were never binding -> both falsified.
//   New structure: block = 64 rows (one chunk), hs frags held in REGISTERS
//   (read once); loop over 8 column-slabs staging 32KB C-slab into LDS from
//   L2 (C = 512KB, resident in every XCD L2 -> off-fabric). Grid = 512
//   chunks x 2 col-halves = 1024 blocks, 4 blocks/CU.
//   Fabric: 134(x) + 34(hs 2x) + 131(y) = 300MB -> floor ~48us.

typedef __attribute__((ext_vector_type(8))) _Float16 half8;
typedef __attribute__((ext_vector_type(4))) float f32x4;

__device__ inline half8 cvt8(float4 a, float4 b) {
  half8 h;
  h[0] = (_Float16)a.x; h[1] = (_Float16)a.y;
  h[2] = (_Float16)a.z; h[3] = (_Float16)a.w;
  h[4] = (_Float16)b.x; h[5] = (_Float16)b.y;
  h[6] = (_Float16)b.z; h[7] = (_Float16)b.w;
  return h;
}

// ---------------------------------------------------------------------------
// Convert B (256x1024) and C (1024x256) to f16. 65536 threads x 8 elems.
// ---------------------------------------------------------------------------
__global__ __launch_bounds__(256) void cvt_bc(
    const float* __restrict__ Bp, const float* __restrict__ Cp,
    _Float16* __restrict__ Bh, _Float16* __restrict__ Ch)
{
  const int g = blockIdx.x * 256 + threadIdx.x;      // 0..65535
  const size_t off = (size_t)(g & 32767) * 8;
  const float* src = (g < 32768) ? (Bp + off) : (Cp + off);
  _Float16*    dst = (g < 32768) ? (Bh + off) : (Ch + off);
  float4 a = *(const float4*)src;
  float4 b = *(const float4*)(src + 4);
  *(half8*)dst = cvt8(a, b);
}

// ---------------------------------------------------------------------------
// GEMM1: Bx[M,256] = x[M,1024] * B[256,1024]^T  (f16 out) + fused scan_E.
// Block = 64 rows (= one scan chunk); wave w owns rows w*16..+15 x ALL 256 n.
// B-slab chunk (256n x 128k f16 = 64KB, XOR-swizzled) in LDS, refilled from
// L2 each K-chunk. A-fragments stream straight from global x.
// Epilogue bounces the 64x256 f16 tile through LDS for coalesced stores AND
// computes E[chunk][n] = 64-step scan sum from the same LDS tile.
// ---------------------------------------------------------------------------
__global__ __launch_bounds__(256) void gemm_bx(
    const float* __restrict__ x, const _Float16* __restrict__ Bh,
    const float* __restrict__ Ap,
    _Float16* __restrict__ Bxh, float* __restrict__ E)
{
  __shared__ _Float16 lb[256 * 128];   // 64KB, [n][k8p*8], k8p = k8 ^ (n&7)

  const int tid  = threadIdx.x;
  const int lane = tid & 63;
  const int wave = tid >> 6;
  const int quad = lane >> 4;
  const int l16  = lane & 15;
  const long blockM = (long)blockIdx.x * 64;
  const long arow = blockM + wave * 16 + l16;     // global A row for frags

  f32x4 acc[16];
  #pragma unroll
  for (int i = 0; i < 16; i++) acc[i] = (f32x4){0.f, 0.f, 0.f, 0.f};

  for (int kc = 0; kc < 8; kc++) {
    __syncthreads();   // previous chunk's readers done
    // fill B-slab: thread t = row n, 16 x 16B from L2-resident Bh
    {
      const int n = tid;
      const _Float16* src = Bh + (size_t)n * 1024 + kc * 128;
      #pragma unroll
      for (int j = 0; j < 16; j++) {
        half8 v = *(const half8*)(src + j * 8);
        const int k8p = j ^ (n & 7);
        *(half8*)&lb[n * 128 + k8p * 8] = v;
      }
    }
    // A-fragments for this chunk (4 ks), direct from x
    half8 af[4];
    #pragma unroll
    for (int ks = 0; ks < 4; ks++) {
      const float* ga = x + arow * 1024 + kc * 128 + ks * 32 + quad * 8;
      float4 a0 = *(const float4*)ga;
      float4 a1 = *(const float4*)(ga + 4);
      af[ks] = cvt8(a0, a1);
    }
    __syncthreads();
    #pragma unroll
    for (int ks = 0; ks < 4; ks++) {
      #pragma unroll
      for (int nt = 0; nt < 16; nt++) {
        const int n   = nt * 16 + l16;
        const int k8p = (ks * 4 + quad) ^ (n & 7);
        half8 bf = *(const half8*)&lb[n * 128 + k8p * 8];
        acc[nt] = __builtin_amdgcn_mfma_f32_16x16x32_f16(af[ks], bf, acc[nt], 0, 0, 0);
      }
    }
  }

  // epilogue: bounce through LDS -> coalesced f16 stores + fused scan_E.
  __syncthreads();
  #pragma unroll
  for (int nt = 0; nt < 16; nt++)
    #pragma unroll
    for (int r = 0; r < 4; r++)
      lb[(wave * 16 + quad * 4 + r) * 256 + nt * 16 + l16] = (_Float16)acc[nt][r];
  __syncthreads();
  {
    const int row = tid >> 2, seg = tid & 3;       // 64 rows x 4 segs
    _Float16* dst = Bxh + (blockM + row) * 256 + seg * 64;
    const _Float16* srcl = &lb[row * 256 + seg * 64];
    #pragma unroll
    for (int j = 0; j < 8; j++)
      *(half8*)(dst + j * 8) = *(const half8*)(srcl + j * 8);
  }
  {
    // fused scan_E: thread tid = state index n; 64-step serial scan over the
    // LDS tile (same f16 values that were just stored -> bit-identical).
    const float al = expf(-expf(Ap[tid]));
    float h = 0.f;
    #pragma unroll 8
    for (int t = 0; t < 64; t++)
      h = fmaf(al, h, (float)lb[t * 256 + tid]);
    E[(size_t)blockIdx.x * 256 + tid] = h;
  }
}

// ---------------------------------------------------------------------------
// scan_prefix: per batch b, serial prefix over 64 chunk sums.
// Bulk-load the 64x256 f32 E-slice (64KB) into LDS with pipelined float4
// loads, then run the serial recurrence out of LDS.
// ---------------------------------------------------------------------------
__global__ __launch_bounds__(256) void scan_prefix(
    const float* __restrict__ E, const float* __restrict__ Ap,
    float* __restrict__ carry)
{
  __shared__ float4 se4[4096];                     // 64KB = 64 chunks x 256 n
  const int n = threadIdx.x;
  const int b = blockIdx.x;

  const float4* src4 = (const float4*)(E + (size_t)b * 64 * 256);
  #pragma unroll
  for (int j = 0; j < 16; j++)
    se4[j * 256 + n] = src4[j * 256 + n];

  const float al = expf(-expf(Ap[n]));
  float aL = al;
  #pragma unroll
  for (int i = 0; i < 6; i++) aL *= aL;            // al^64

  __syncthreads();
  const float* se = (const float*)se4;
  float run = 0.f;
  for (int c = 0; c < 64; c++) {
    carry[((size_t)b * 64 + c) * 256 + n] = run;
    run = fmaf(aL, run, se[c * 256 + n]);
  }
}

__global__ __launch_bounds__(256) void scan_apply(
    _Float16* __restrict__ Bxh, const float* __restrict__ Ap,
    const float* __restrict__ carry)
{
  const int n  = threadIdx.x;
  const int bc = blockIdx.x;
  const float al = expf(-expf(Ap[n]));
  float h = carry[(size_t)bc * 256 + n];
  const size_t base = (size_t)bc * 64 * 256 + n;
  #pragma unroll 16
  for (int t = 0; t < 64; t++) {
    const size_t i = base + (size_t)t * 256;
    h = fmaf(al, h, (float)Bxh[i]);
    Bxh[i] = (_Float16)h;
  }
}

// ---------------------------------------------------------------------------
// GEMM2: y[M,1024] = hs[M,256] * C[1024,256]^T + D*x
// R4: loop-nest inversion. Block = one 64-row chunk x one 512-col half.
// hs fragments (af[8], 32 VGPR) loaded ONCE per wave from HBM; loop over
// 8 column-slabs of 64 cols, staging the 32KB XOR-swizzled C-slab into LDS
// from L2-resident Ch each iteration. Swapped-operand MFMA (R3 layout,
// harness-verified): lane owns y[row=rowbase+l16][4 consecutive cols] ->
// float4 x/D loads + float4 y stores.
// Fabric traffic: x once, y once, hs twice, C from L2 -> ~300MB total.
// ---------------------------------------------------------------------------
__global__ __launch_bounds__(256, 4) void gemm_y(
    const _Float16* __restrict__ hs, const _Float16* __restrict__ Ch,
    const float* __restrict__ x, const float* __restrict__ Dp,
    float* __restrict__ y)
{
  __shared__ _Float16 lc[64 * 256];   // 32KB, [n_local][k8p*8]

  const int tid  = threadIdx.x;
  const int lane = tid & 63;
  const int wave = tid >> 6;          // 0..3
  const int quad = lane >> 4;
  const int l16  = lane & 15;
  const int cg   = blockIdx.x & 1;    // column half: cols cg*512 .. +511
  const long mg  = blockIdx.x >> 1;   // chunk 0..511
  const long row = mg * 64 + wave * 16 + l16;   // this lane's y row

  // hs fragments for this wave's 16 rows, all 256 k: read ONCE.
  half8 af[8];
  {
    const _Float16* ph = hs + row * 256;
    #pragma unroll
    for (int ks = 0; ks < 8; ks++)
      af[ks] = *(const half8*)(ph + ks * 32 + quad * 8);
  }

  const int nfill = tid >> 2, qfill = tid & 3;  // C-slab fill role

  for (int it = 0; it < 8; it++) {
    const int n0 = cg * 512 + it * 64;

    if (it) __syncthreads();          // prev slab's readers done
    // fill C-slab: thread -> n = tid>>2 (0..63), q = tid&3 (8 x 16B)
    {
      const _Float16* src = Ch + (size_t)(n0 + nfill) * 256 + qfill * 64;
      #pragma unroll
      for (int j = 0; j < 8; j++) {
        half8 v = *(const half8*)(src + j * 8);
        const int k8p = (qfill * 8 + j) ^ (nfill & 7);
        *(half8*)&lc[nfill * 256 + k8p * 8] = v;
      }
    }

    // independent of LDS: this lane's x tile + D for this slab (issue early)
    const float* px = x + row * 1024 + n0 + quad * 4;
    const float* pD = Dp + n0 + quad * 4;
    float4 xv[4], dv[4];
    #pragma unroll
    for (int nt = 0; nt < 4; nt++) {
      xv[nt] = *(const float4*)(px + nt * 16);
      dv[nt] = *(const float4*)(pD + nt * 16);
    }

    __syncthreads();                  // slab visible

    f32x4 acc[4];
    #pragma unroll
    for (int nt = 0; nt < 4; nt++) acc[nt] = (f32x4){0.f, 0.f, 0.f, 0.f};

    #pragma unroll
    for (int ks = 0; ks < 8; ks++) {
      #pragma unroll
      for (int nt = 0; nt < 4; nt++) {
        const int nl  = nt * 16 + l16;
        const int k8p = (ks * 4 + quad) ^ (nl & 7);
        half8 cf = *(const half8*)&lc[nl * 256 + k8p * 8];
        acc[nt] = __builtin_amdgcn_mfma_f32_16x16x32_f16(cf, af[ks], acc[nt], 0, 0, 0);
      }
    }

    // epilogue: y = acc + D*x, 4 consecutive cols per lane (float4 stores)
    float* py = y + row * 1024 + n0 + quad * 4;
    #pragma unroll
    for (int nt = 0; nt < 4; nt++) {
      float4 o;
      o.x = acc[nt][0] + dv[nt].x * xv[nt].x;
      o.y = acc[nt][1] + dv[nt].y * xv[nt].y;
      o.z = acc[nt][2] + dv[nt].z * xv[nt].z;
      o.w = acc[nt][3] + dv[nt].w * xv[nt].w;
      *(float4*)(py + nt * 16) = o;
    }
  }
}

// ---------------------------------------------------------------------------
extern "C" void kernel_launch(void* const* d_in, const int* in_sizes, int n_in,
                              void* d_out, int out_size, void* d_ws, size_t ws_size,
                              hipStream_t stream) {
  const float* x  = (const float*)d_in[0];
  const float* Ap = (const float*)d_in[1];
  const float* Bp = (const float*)d_in[2];
  const float* Cp = (const float*)d_in[3];
  const float* Dp = (const float*)d_in[4];
  float* y = (float*)d_out;

  // ws: Bxh 16.8MB | Bh 512KB | Ch 512KB | E 512KB | carry 512KB
  _Float16* Bxh = (_Float16*)d_ws;
  _Float16* Bh  = Bxh + (size_t)32768 * 256;
  _Float16* Ch  = Bh + (size_t)256 * 1024;
  float* E      = (float*)(Ch + (size_t)1024 * 256);
  float* carry  = E + (size_t)512 * 256;

  cvt_bc     <<<256,  256, 0, stream>>>(Bp, Cp, Bh, Ch);
  gemm_bx    <<<512,  256, 0, stream>>>(x, Bh, Ap, Bxh, E);
  scan_prefix<<<8,    256, 0, stream>>>(E, Ap, carry);
  scan_apply <<<512,  256, 0, stream>>>(Bxh, Ap, carry);
  gemm_y     <<<1024, 256, 0, stream>>>(Bxh, Ch, x, Dp, y);
}